// Round 4
// baseline (322.852 us; speedup 1.0000x reference)
//
#include <hip/hip_runtime.h>

typedef unsigned short u16;
typedef __attribute__((ext_vector_type(8))) short bf16x8;
typedef __attribute__((ext_vector_type(4))) float f32x4;
typedef __attribute__((ext_vector_type(4))) unsigned short u16x4;

__device__ __forceinline__ u16 f2bf(float f) {
  union { float f; unsigned u; } v; v.f = f;
  return (u16)((v.u + 0x7FFFu + ((v.u >> 16) & 1u)) >> 16);
}

__device__ __forceinline__ void gload16(const u16* g, u16* l) {
  __builtin_amdgcn_global_load_lds((const __attribute__((address_space(1))) void*)g,
                                   (__attribute__((address_space(3))) void*)l, 16, 0, 0);
}

// ---------------- fp32 -> bf16 convert (5 tensors fused) ----------------
__global__ __launch_bounds__(256) void k_f2bf5(
    const float* __restrict__ i0, const float* __restrict__ i1, const float* __restrict__ i2,
    const float* __restrict__ i3, const float* __restrict__ i4,
    u16* o0, u16* o1, u16* o2, u16* o3, u16* o4, int n4x, int n4w) {
  const int seg = blockIdx.y;
  const float* in = (seg == 0) ? i0 : (seg == 1) ? i1 : (seg == 2) ? i2 : (seg == 3) ? i3 : i4;
  u16* out = (seg == 0) ? o0 : (seg == 1) ? o1 : (seg == 2) ? o2 : (seg == 3) ? o3 : o4;
  const int n4 = (seg == 0) ? n4x : n4w;
  int i = blockIdx.x * 256 + threadIdx.x;
  const int stride = gridDim.x * 256;
  for (; i < n4; i += stride) {
    const float4 v = ((const float4*)in)[i];
    u16x4 o;
    o.x = f2bf(v.x); o.y = f2bf(v.y); o.z = f2bf(v.z); o.w = f2bf(v.w);
    ((u16x4*)out)[i] = o;
  }
}

// ---------------- 256x256 8-phase GEMM: C = A[M,K] * Bt[N,K]^T + bias ----------------
// 512 threads = 8 waves (2M x 4N); per-wave 128x64 output (8x4 16x16 frags).
// BK=64, LDS 128 KiB double-buffered, T2 XOR swizzle (chunk ^= row&7, inverse on
// global source), phases: {ds_read|stage} -> barrier -> lgkm0 -> setprio -> 16 MFMA.
// N may span up to 3 concatenated 2048-col output segments (fused QKV).
#define LDA(AS, mh) do { _Pragma("unroll") \
  for (int mi = 0; mi < 4; ++mi) { \
    a[mi][0] = *(const bf16x8*)&(AS)[aBase + ((mh)*4+mi)*1024 + pc0]; \
    a[mi][1] = *(const bf16x8*)&(AS)[aBase + ((mh)*4+mi)*1024 + pc1]; } } while(0)

#define LDB(BS, nh) do { _Pragma("unroll") \
  for (int ni = 0; ni < 2; ++ni) { \
    b[nh][ni][0] = *(const bf16x8*)&(BS)[bBase + ((nh)*2+ni)*1024 + pc0]; \
    b[nh][ni][1] = *(const bf16x8*)&(BS)[bBase + ((nh)*2+ni)*1024 + pc1]; } } while(0)

#define MM(mh, nh) do { _Pragma("unroll") \
  for (int mi = 0; mi < 4; ++mi) { _Pragma("unroll") \
    for (int ni = 0; ni < 2; ++ni) { \
      acc[(mh)*4+mi][(nh)*2+ni] = __builtin_amdgcn_mfma_f32_16x16x32_bf16( \
          a[mi][0], b[nh][ni][0], acc[(mh)*4+mi][(nh)*2+ni], 0, 0, 0); \
      acc[(mh)*4+mi][(nh)*2+ni] = __builtin_amdgcn_mfma_f32_16x16x32_bf16( \
          a[mi][1], b[nh][ni][1], acc[(mh)*4+mi][(nh)*2+ni], 0, 0, 0); } } } while(0)

#define MFMA_FENCE do { asm volatile("s_waitcnt lgkmcnt(0)" ::: "memory"); \
  __builtin_amdgcn_sched_barrier(0); } while(0)

#define KTILE(AS, BS, AN, BN_, tn) do { \
  /* phase 0: stage next tile + ds_read A-half0, B both halves */ \
  if ((tn) < NT) { const long kofs = (long)(tn) << 6; \
    _Pragma("unroll") for (int i = 0; i < 4; ++i) { \
      gload16(A  + (row0 + sRow[i]) * (long)K + kofs + sCol[i], &(AN)[(wid*4+i)*512]); \
      gload16(Bt + (col0 + sRow[i]) * (long)K + kofs + sCol[i], &(BN_)[(wid*4+i)*512]); } } \
  LDA(AS, 0); LDB(BS, 0); LDB(BS, 1); \
  __builtin_amdgcn_s_barrier(); \
  MFMA_FENCE; \
  __builtin_amdgcn_s_setprio(1); MM(0, 0); __builtin_amdgcn_s_setprio(0); \
  __builtin_amdgcn_s_barrier(); \
  /* phase 1 */ \
  __builtin_amdgcn_s_setprio(1); MM(0, 1); __builtin_amdgcn_s_setprio(0); \
  __builtin_amdgcn_s_barrier(); \
  /* phase 2: ds_read A-half1 */ \
  LDA(AS, 1); \
  MFMA_FENCE; \
  __builtin_amdgcn_s_setprio(1); MM(1, 0); __builtin_amdgcn_s_setprio(0); \
  __builtin_amdgcn_s_barrier(); \
  /* phase 3 */ \
  __builtin_amdgcn_s_setprio(1); MM(1, 1); __builtin_amdgcn_s_setprio(0); \
  asm volatile("s_waitcnt vmcnt(0)" ::: "memory"); \
  __builtin_amdgcn_s_barrier(); \
} while(0)

template <int OUT_F32>
__global__ __launch_bounds__(512, 2) void k_gemm256(
    const u16* __restrict__ A, const u16* __restrict__ Bt,
    const float* __restrict__ b0, const float* __restrict__ b1, const float* __restrict__ b2,
    u16* __restrict__ C0, u16* __restrict__ C1, u16* __restrict__ C2,
    float* __restrict__ Cf, int NBM, int K)
{
  __shared__ alignas(16) u16 A0s[16384], B0s[16384], A1s[16384], B1s[16384];

  const int tid = threadIdx.x;
  const int lane = tid & 63, wid = tid >> 6;
  const int fr = lane & 15, fg = lane >> 4;
  const int wr = wid >> 2, wc = wid & 3;

  // bijective XCD-chunked block mapping (m204): consecutive wgid share an XCD.
  const int nblk = gridDim.x;
  const int q = nblk >> 3, r = nblk & 7;
  const int xcd = blockIdx.x & 7, lid = blockIdx.x >> 3;
  const int wgid = (xcd < r ? xcd * (q + 1) : r * (q + 1) + (xcd - r) * q) + lid;
  const int mb = wgid % NBM, nb = wgid / NBM;
  const long row0 = (long)mb * 256;
  const long col0 = (long)nb * 256;

  // staging: 2048 16B-chunks per tile, 4 per thread; linear LDS dest,
  // inverse-swizzled global source column.
  int sRow[4], sCol[4];
#pragma unroll
  for (int i = 0; i < 4; ++i) {
    const int s = (wid * 4 + i) * 64 + lane;
    sRow[i] = s >> 3;
    sCol[i] = ((s & 7) ^ ((s >> 3) & 7)) << 3;
  }

  // ds_read bases (u16 units); swizzled chunk ids hoisted per-lane
  const int sw = fr & 7;
  const int aBase = (wr * 128 + fr) * 64;
  const int bBase = (wc * 64 + fr) * 64;
  const int pc0 = (fg ^ sw) << 3;
  const int pc1 = ((4 + fg) ^ sw) << 3;

  f32x4 acc[8][4] = {};
  bf16x8 a[4][2], b[2][2][2];

  const int NT = K >> 6;

  // prologue: stage tile 0 into buffer 0
#pragma unroll
  for (int i = 0; i < 4; ++i) {
    gload16(A  + (row0 + sRow[i]) * (long)K + sCol[i], &A0s[(wid * 4 + i) * 512]);
    gload16(Bt + (col0 + sRow[i]) * (long)K + sCol[i], &B0s[(wid * 4 + i) * 512]);
  }
  asm volatile("s_waitcnt vmcnt(0)" ::: "memory");
  __builtin_amdgcn_s_barrier();

  for (int t = 0; t < NT; t += 2) {
    KTILE(A0s, B0s, A1s, B1s, t + 1);
    KTILE(A1s, B1s, A0s, B0s, t + 2);
  }

  // epilogue: C/D col = lane&15, row = (lane>>4)*4+reg; bias + segment select
  const int seg = (int)(col0 >> 11);
  const long colL = col0 & 2047;
  const float* bp = (seg == 0) ? b0 : (seg == 1) ? b1 : b2;
  u16* Cb = (seg == 0) ? C0 : (seg == 1) ? C1 : C2;
#pragma unroll
  for (int n = 0; n < 4; ++n) {
    const long cN = colL + wc * 64 + n * 16 + fr;
    const float bv = bp[cN];
#pragma unroll
    for (int m = 0; m < 8; ++m) {
      const long rM = row0 + wr * 128 + m * 16 + fg * 4;
#pragma unroll
      for (int reg = 0; reg < 4; ++reg) {
        const float v = acc[m][n][reg] + bv;
        if (OUT_F32) Cf[(rM + reg) * 2048 + cN] = v;
        else         Cb[(rM + reg) * 2048 + cN] = f2bf(v);
      }
    }
  }
}

// ---------------- V transpose: V[b][s][h*128+d] -> Vt[(b*16+h)*128+d][s] ----------------
__global__ __launch_bounds__(256) void k_transpose_v(const u16* __restrict__ V,
                                                     u16* __restrict__ Vt) {
  __shared__ u16 t[64][68];
  const int bh = blockIdx.z;
  const long s0 = (long)blockIdx.x * 64;
  const long d0 = (long)blockIdx.y * 64;
  const int tid = threadIdx.x;
  const long rowbase = (long)(bh >> 4) * 2048;
  const int hcol = (bh & 15) * 128;
#pragma unroll
  for (int i = 0; i < 4; ++i) {
    const int v = tid + i * 256;
    const int r = v >> 4, c4 = (v & 15) << 2;
    const u16x4 val = *(const u16x4*)&V[(rowbase + s0 + r) * 2048 + hcol + d0 + c4];
    *(u16x4*)&t[r][c4] = val;
  }
  __syncthreads();
#pragma unroll
  for (int i = 0; i < 4; ++i) {
    const int v = tid + i * 256;
    const int dr = v >> 4, s4 = (v & 15) << 2;
    u16x4 o;
    o.x = t[s4 + 0][dr]; o.y = t[s4 + 1][dr]; o.z = t[s4 + 2][dr]; o.w = t[s4 + 3][dr];
    *(u16x4*)&Vt[((long)bh * 128 + d0 + dr) * 2048 + s0 + s4] = o;
  }
}

// ---------------- causal flash attention (unchanged from round 3) ----------------
__global__ __launch_bounds__(512) void k_flash_attn(
    const u16* __restrict__ Q, const u16* __restrict__ K, const u16* __restrict__ Vt,
    u16* __restrict__ O)
{
  __shared__ alignas(16) u16 Kt[2][8192];    // [64 kv][128 d], swizzled
  __shared__ alignas(16) u16 Vtt[2][8192];   // [128 d][64 s], swizzled
  __shared__ alignas(16) u16 Plds[8][16][72];

  const int tid = threadIdx.x;
  const int lane = tid & 63, wid = tid >> 6;
  const int fr = lane & 15, fg = lane >> 4;

  const int L = blockIdx.x;
  const int bh = (L & 7) * 4 + ((L >> 3) & 3);
  const int bx = L >> 5;

  const long rowbase = (long)(bh >> 4) * 2048;
  const int hcol = (bh & 15) * 128;
  const u16* Kg = K + rowbase * 2048 + hcol;
  const u16* Vg = Vt + (long)bh * 128 * 2048;
  const float scale2 = 0.08838834764831845f * 1.44269504089f;  // 1/sqrt(128) * log2(e)

  int kR[2], kC[2], vR[2], vC[2];
#pragma unroll
  for (int i = 0; i < 2; ++i) {
    const int chunk = (wid * 2 + i) * 64 + lane;
    kR[i] = chunk >> 4;
    kC[i] = ((chunk & 15) ^ (kR[i] & 7)) << 3;
    vR[i] = chunk >> 3;
    vC[i] = ((chunk & 7) ^ (vR[i] & 7)) << 3;
  }

  const int sw = fr & 7;
  int kbase[4], vbase[2];
#pragma unroll
  for (int c = 0; c < 4; ++c) kbase[c] = fr * 128 + (((c * 4 + fg) ^ sw) << 3);
#pragma unroll
  for (int kc = 0; kc < 2; ++kc) vbase[kc] = fr * 64 + (((kc * 4 + fg) ^ sw) << 3);

  for (int pass = 0; pass < 2; ++pass) {
    const int qblk = pass ? (15 - bx) : bx;
    const int n = 2 * (qblk + 1);
    const int q_lo = qblk * 128 + wid * 16;

    bf16x8 qf[4];
#pragma unroll
    for (int c = 0; c < 4; ++c)
      qf[c] = *(const bf16x8*)&Q[(rowbase + q_lo + fr) * 2048 + hcol + c * 32 + fg * 8];

    f32x4 oacc[8] = {};
    float m_run[4], l_run[4];
#pragma unroll
    for (int r = 0; r < 4; ++r) { m_run[r] = -1e30f; l_run[r] = 0.0f; }

#pragma unroll
    for (int i = 0; i < 2; ++i) {
      gload16(Kg + (long)kR[i] * 2048 + kC[i], &Kt[0][(wid * 2 + i) * 512]);
      gload16(Vg + (long)vR[i] * 2048 + vC[i], &Vtt[0][(wid * 2 + i) * 512]);
    }

    int cur = 0;
    for (int j = 0; j < n; ++j) {
      if (j + 1 < n) {
        const long kv = (long)(j + 1) * 64;
#pragma unroll
        for (int i = 0; i < 2; ++i) {
          gload16(Kg + (kv + kR[i]) * 2048 + kC[i], &Kt[cur ^ 1][(wid * 2 + i) * 512]);
          gload16(Vg + (long)vR[i] * 2048 + kv + vC[i], &Vtt[cur ^ 1][(wid * 2 + i) * 512]);
        }
        asm volatile("s_waitcnt vmcnt(4)" ::: "memory");
      } else {
        asm volatile("s_waitcnt vmcnt(0)" ::: "memory");
      }
      __builtin_amdgcn_s_barrier();
      __builtin_amdgcn_sched_barrier(0);

      const int kvlo = j * 64;
      const bool skip = (kvlo >= q_lo + 16);
      if (!skip) {
        const bool needmask = (kvlo + 63 > q_lo);

        f32x4 st[4] = {};
        const u16* kt = Kt[cur];
#pragma unroll
        for (int t = 0; t < 4; ++t)
#pragma unroll
          for (int c = 0; c < 4; ++c) {
            const bf16x8 kf = *(const bf16x8*)&kt[kbase[c] + t * 2048];
            st[t] = __builtin_amdgcn_mfma_f32_16x16x32_bf16(qf[c], kf, st[t], 0, 0, 0);
          }

        float pmax[4] = {-1e30f, -1e30f, -1e30f, -1e30f};
        if (needmask) {
#pragma unroll
          for (int t = 0; t < 4; ++t) {
            const int kg = kvlo + t * 16 + fr;
#pragma unroll
            for (int r = 0; r < 4; ++r) {
              const int qg = q_lo + fg * 4 + r;
              const float v = (kg <= qg) ? st[t][r] * scale2 : -1e30f;
              st[t][r] = v;
              pmax[r] = fmaxf(pmax[r], v);
            }
          }
        } else {
#pragma unroll
          for (int t = 0; t < 4; ++t)
#pragma unroll
            for (int r = 0; r < 4; ++r) {
              const float v = st[t][r] * scale2;
              st[t][r] = v;
              pmax[r] = fmaxf(pmax[r], v);
            }
        }
#pragma unroll
        for (int d = 1; d < 16; d <<= 1)
#pragma unroll
          for (int r = 0; r < 4; ++r) pmax[r] = fmaxf(pmax[r], __shfl_xor(pmax[r], d));

        const int ok = (pmax[0] <= m_run[0] + 8.f) & (pmax[1] <= m_run[1] + 8.f) &
                       (pmax[2] <= m_run[2] + 8.f) & (pmax[3] <= m_run[3] + 8.f);
        if (!__all(ok)) {
#pragma unroll
          for (int r = 0; r < 4; ++r) {
            const float nm = fmaxf(m_run[r], pmax[r]);
            const float al = exp2f(m_run[r] - nm);
            l_run[r] *= al;
            m_run[r] = nm;
#pragma unroll
            for (int dt = 0; dt < 8; ++dt) oacc[dt][r] *= al;
          }
        }

        float lsum[4] = {0.f, 0.f, 0.f, 0.f};
#pragma unroll
        for (int t = 0; t < 4; ++t)
#pragma unroll
          for (int r = 0; r < 4; ++r) {
            const float p = exp2f(st[t][r] - m_run[r]);
            st[t][r] = p;
            lsum[r] += p;
          }
#pragma unroll
        for (int d = 1; d < 16; d <<= 1)
#pragma unroll
          for (int r = 0; r < 4; ++r) lsum[r] += __shfl_xor(lsum[r], d);
#pragma unroll
        for (int r = 0; r < 4; ++r) l_run[r] += lsum[r];

#pragma unroll
        for (int t = 0; t < 4; ++t)
#pragma unroll
          for (int r = 0; r < 4; ++r)
            Plds[wid][fg * 4 + r][t * 16 + fr] = f2bf(st[t][r]);
        asm volatile("s_waitcnt lgkmcnt(0)" ::: "memory");
        __builtin_amdgcn_sched_barrier(0);

        const u16* vt = Vtt[cur];
#pragma unroll
        for (int kc = 0; kc < 2; ++kc) {
          const bf16x8 pf = *(const bf16x8*)&Plds[wid][fr][kc * 32 + fg * 8];
#pragma unroll
          for (int dt = 0; dt < 8; ++dt) {
            const bf16x8 vf = *(const bf16x8*)&vt[vbase[kc] + dt * 1024];
            oacc[dt] = __builtin_amdgcn_mfma_f32_16x16x32_bf16(pf, vf, oacc[dt], 0, 0, 0);
          }
        }
      }

      asm volatile("" ::: "memory");
      __builtin_amdgcn_s_barrier();
      cur ^= 1;
    }

    float inv[4];
#pragma unroll
    for (int r = 0; r < 4; ++r) inv[r] = 1.0f / l_run[r];
#pragma unroll
    for (int dt = 0; dt < 8; ++dt)
#pragma unroll
      for (int r = 0; r < 4; ++r)
        O[(rowbase + q_lo + fg * 4 + r) * 2048 + hcol + dt * 16 + fr] = f2bf(oacc[dt][r] * inv[r]);
  }
}

extern "C" void kernel_launch(void* const* d_in, const int* in_sizes, int n_in,
                              void* d_out, int out_size, void* d_ws, size_t ws_size,
                              hipStream_t stream) {
  const float* x  = (const float*)d_in[0];
  const float* Wq = (const float*)d_in[1];
  const float* bq = (const float*)d_in[2];
  const float* Wk = (const float*)d_in[3];
  const float* bk = (const float*)d_in[4];
  const float* Wv = (const float*)d_in[5];
  const float* bv = (const float*)d_in[6];
  const float* Wo = (const float*)d_in[7];
  const float* bo = (const float*)d_in[8];
  float* out = (float*)d_out;

  const int M = 4096, Kd = 2048;
  char* ws = (char*)d_ws;
  const size_t SZ_X = 16777216;   // 8M bf16
  const size_t SZ_W = 8388608;    // 4M bf16
  u16* xb  = (u16*)(ws);
  u16* wqb = (u16*)(ws + SZ_X);                 // wq/wk/wv contiguous = [6144][2048]
  u16* wkb = (u16*)(ws + SZ_X + 1 * SZ_W);
  u16* wvb = (u16*)(ws + SZ_X + 2 * SZ_W);
  u16* wob = (u16*)(ws + SZ_X + 3 * SZ_W);
  u16* Qb  = (u16*)(ws + 1 * SZ_X + 4 * SZ_W);
  u16* Kb  = (u16*)(ws + 2 * SZ_X + 4 * SZ_W);
  u16* Vb  = (u16*)(ws + 3 * SZ_X + 4 * SZ_W);
  u16* Vtb = (u16*)(ws + 4 * SZ_X + 4 * SZ_W);
  u16* Ob  = Vb;   // V dead after transpose; reuse for attention output

  k_f2bf5<<<dim3(1024, 5), 256, 0, stream>>>(x, Wq, Wk, Wv, Wo,
                                             xb, wqb, wkb, wvb, wob,
                                             8388608 / 4, 4194304 / 4);

  // fused QKV: one GEMM, M=4096 x N=6144 x K=2048; epilogue splits into Q/K/V
  k_gemm256<0><<<384, 512, 0, stream>>>(xb, wqb, bq, bk, bv, Qb, Kb, Vb, nullptr, 16, Kd);

  k_transpose_v<<<dim3(32, 2, 32), 256, 0, stream>>>(Vb, Vtb);

  k_flash_attn<<<256, 512, 0, stream>>>(Qb, Kb, Vtb, Ob);

  // output projection (fp32 out), M=4096 x N=2048 x K=2048
  k_gemm256<1><<<128, 512, 0, stream>>>(Ob, wob, bo, bo, bo, nullptr, nullptr, nullptr, out, 16, Kd);
}

// Round 5
// 296.525 us; speedup vs baseline: 1.0888x; 1.0888x over previous
//
#include <hip/hip_runtime.h>

typedef unsigned short u16;
typedef __attribute__((ext_vector_type(8))) short bf16x8;
typedef __attribute__((ext_vector_type(4))) float f32x4;
typedef __attribute__((ext_vector_type(4))) unsigned short u16x4;

__device__ __forceinline__ u16 f2bf(float f) {
  union { float f; unsigned u; } v; v.f = f;
  return (u16)((v.u + 0x7FFFu + ((v.u >> 16) & 1u)) >> 16);
}

__device__ __forceinline__ void gload16(const u16* g, u16* l) {
  __builtin_amdgcn_global_load_lds((const __attribute__((address_space(1))) void*)g,
                                   (__attribute__((address_space(3))) void*)l, 16, 0, 0);
}

// ---------------- fp32 -> bf16 convert (5 tensors fused) ----------------
__global__ __launch_bounds__(256) void k_f2bf5(
    const float* __restrict__ i0, const float* __restrict__ i1, const float* __restrict__ i2,
    const float* __restrict__ i3, const float* __restrict__ i4,
    u16* o0, u16* o1, u16* o2, u16* o3, u16* o4, int n4x, int n4w) {
  const int seg = blockIdx.y;
  const float* in = (seg == 0) ? i0 : (seg == 1) ? i1 : (seg == 2) ? i2 : (seg == 3) ? i3 : i4;
  u16* out = (seg == 0) ? o0 : (seg == 1) ? o1 : (seg == 2) ? o2 : (seg == 3) ? o3 : o4;
  const int n4 = (seg == 0) ? n4x : n4w;
  int i = blockIdx.x * 256 + threadIdx.x;
  const int stride = gridDim.x * 256;
  for (; i < n4; i += stride) {
    const float4 v = ((const float4*)in)[i];
    u16x4 o;
    o.x = f2bf(v.x); o.y = f2bf(v.y); o.z = f2bf(v.z); o.w = f2bf(v.w);
    ((u16x4*)out)[i] = o;
  }
}

// ---------------- 128x256 GEMM, counted-vmcnt 2-phase schedule ----------------
// C[M,2048-seg] = A[M,2048] * Bt[N,2048]^T + bias. 512 thr = 8 waves (2M x 4N),
// per-wave 64x64 out (4x4 16x16 frags). BK=64, LDS 96 KiB dbuf, T2 XOR swizzle.
// Staging units: P0 = A-tile + B-rows((r&63)<32)  [4 loads/thr]
//                P1 = B-rows((r&63)>=32)          [2 loads/thr]
// Derived waits: P0 vmcnt(4) (drains unitP1(t));  P1 vmcnt(2) (drains unitP0(t+1)).
// In-flight never 0 in the main loop (T4); vmcnt(0) only at last tile.
#define STAGE_P0(AN, BN_, kofs) do { _Pragma("unroll") \
  for (int i = 0; i < 2; ++i) { \
    gload16(A  + (row0 + aRow[i]) * 2048L + (kofs) + aCol[i], &(AN)[aDst[i]]); \
    gload16(Bt + (col0 + brLo[i]) * 2048L + (kofs) + bcB[i], &(BN_)[bDstLo[i]]); } } while (0)

#define STAGE_P1(BN_, kofs) do { _Pragma("unroll") \
  for (int i = 0; i < 2; ++i) \
    gload16(Bt + (col0 + brLo[i] + 32) * 2048L + (kofs) + bcB[i], &(BN_)[bDstLo[i] + 2048]); } while (0)

#define MMpair(nbase) do { _Pragma("unroll") \
  for (int mi = 0; mi < 4; ++mi) { _Pragma("unroll") \
    for (int nn = 0; nn < 2; ++nn) { \
      acc[mi][(nbase) + nn] = __builtin_amdgcn_mfma_f32_16x16x32_bf16( \
          a[mi][0], b[nn][0], acc[mi][(nbase) + nn], 0, 0, 0); \
      acc[mi][(nbase) + nn] = __builtin_amdgcn_mfma_f32_16x16x32_bf16( \
          a[mi][1], b[nn][1], acc[mi][(nbase) + nn], 0, 0, 0); } } } while (0)

#define TILE(AS, BS, AN, BN_, tn, full) do { \
  _Pragma("unroll") for (int mi = 0; mi < 4; ++mi) { \
    a[mi][0] = *(const bf16x8*)&(AS)[aBase + mi * 1024 + pc0]; \
    a[mi][1] = *(const bf16x8*)&(AS)[aBase + mi * 1024 + pc1]; } \
  _Pragma("unroll") for (int nn = 0; nn < 2; ++nn) { \
    b[nn][0] = *(const bf16x8*)&(BS)[bBase + nn * 1024 + pc0]; \
    b[nn][1] = *(const bf16x8*)&(BS)[bBase + nn * 1024 + pc1]; } \
  if (full) { STAGE_P0(AN, BN_, (long)(tn) << 6); \
    asm volatile("s_waitcnt vmcnt(4)" ::: "memory"); \
  } else { asm volatile("s_waitcnt vmcnt(0)" ::: "memory"); } \
  __builtin_amdgcn_s_barrier(); \
  asm volatile("s_waitcnt lgkmcnt(0)" ::: "memory"); \
  __builtin_amdgcn_sched_barrier(0); \
  __builtin_amdgcn_s_setprio(1); MMpair(0); __builtin_amdgcn_s_setprio(0); \
  __builtin_amdgcn_s_barrier(); \
  _Pragma("unroll") for (int nn = 0; nn < 2; ++nn) { \
    b[nn][0] = *(const bf16x8*)&(BS)[bBase + (2 + nn) * 1024 + pc0]; \
    b[nn][1] = *(const bf16x8*)&(BS)[bBase + (2 + nn) * 1024 + pc1]; } \
  if (full) { STAGE_P1(BN_, (long)(tn) << 6); \
    asm volatile("s_waitcnt vmcnt(2)" ::: "memory"); \
  } else { asm volatile("s_waitcnt vmcnt(0)" ::: "memory"); } \
  __builtin_amdgcn_s_barrier(); \
  asm volatile("s_waitcnt lgkmcnt(0)" ::: "memory"); \
  __builtin_amdgcn_sched_barrier(0); \
  __builtin_amdgcn_s_setprio(1); MMpair(2); __builtin_amdgcn_s_setprio(0); \
  __builtin_amdgcn_s_barrier(); \
} while (0)

template <int OUT_F32>
__global__ __launch_bounds__(512, 2) void k_gemm256(
    const u16* __restrict__ A, const u16* __restrict__ Bt,
    const float* __restrict__ b0, const float* __restrict__ b1, const float* __restrict__ b2,
    u16* __restrict__ C0, u16* __restrict__ C1, u16* __restrict__ C2,
    float* __restrict__ Cf, int NBM)
{
  __shared__ alignas(16) u16 A0s[8192], B0s[16384], A1s[8192], B1s[16384];

  const int tid = threadIdx.x;
  const int lane = tid & 63, wid = tid >> 6;
  const int fr = lane & 15, fg = lane >> 4;
  const int wr = wid >> 2, wc = wid & 3;

  // bijective XCD-chunked block mapping: consecutive wgid share an XCD
  const int nblk = gridDim.x;
  const int q = nblk >> 3, r = nblk & 7;
  const int xcd = blockIdx.x & 7, lid = blockIdx.x >> 3;
  const int wgid = (xcd < r ? xcd * (q + 1) : r * (q + 1) + (xcd - r) * q) + lid;
  const int mb = wgid % NBM, nb = wgid / NBM;
  const long row0 = (long)mb * 128;
  const long col0 = (long)nb * 256;

  // staging assignment (2 chunk-ids per thread; per-wave spans of 64 stay contiguous)
  int aRow[2], aCol[2], brLo[2], bcB[2], aDst[2], bDstLo[2];
#pragma unroll
  for (int i = 0; i < 2; ++i) {
    const int g = (wid * 2 + i) * 64 + lane;          // 0..1023
    aRow[i] = g >> 3;                                  // A: 128 rows x 8 chunks
    aCol[i] = ((g & 7) ^ (aRow[i] & 7)) << 3;
    aDst[i] = g * 8;                                   // u16 units
    const int stripe = g >> 8, rowin = (g >> 3) & 31;  // B-low: 4 stripes of 32 rows
    brLo[i] = stripe * 64 + rowin;
    bcB[i] = ((g & 7) ^ (brLo[i] & 7)) << 3;           // (row+32)&7 == row&7
    bDstLo[i] = stripe * 4096 + (g & 255) * 8;         // u16 units
  }

  // ds_read bases (u16 units), T2-swizzled chunk offsets
  const int sw = fr & 7;
  const int aBase = (wr * 64 + fr) * 64;
  const int bBase = (wc * 64 + fr) * 64;
  const int pc0 = (fg ^ sw) << 3;
  const int pc1 = ((4 + fg) ^ sw) << 3;

  f32x4 acc[4][4] = {};
  bf16x8 a[4][2], b[2][2];

  // prologue: stage tile 0 fully into buffer 0
  STAGE_P0(A0s, B0s, 0);
  STAGE_P1(B0s, 0);
  asm volatile("s_waitcnt vmcnt(0)" ::: "memory");
  __builtin_amdgcn_s_barrier();

#pragma unroll 1
  for (int t = 0; t < 30; t += 2) {
    TILE(A0s, B0s, A1s, B1s, t + 1, 1);
    TILE(A1s, B1s, A0s, B0s, t + 2, 1);
  }
  TILE(A0s, B0s, A1s, B1s, 31, 1);
  TILE(A1s, B1s, A0s, B0s, 32, 0);

  // epilogue: C/D col = lane&15, row = (lane>>4)*4+reg; bias + segment select
  const int seg = (int)(col0 >> 11);
  const long colL = col0 & 2047;
  const float* bp = (seg == 0) ? b0 : (seg == 1) ? b1 : b2;
  u16* Cb = (seg == 0) ? C0 : (seg == 1) ? C1 : C2;
#pragma unroll
  for (int n = 0; n < 4; ++n) {
    const long cN = colL + wc * 64 + n * 16 + fr;
    const float bv = bp[cN];
#pragma unroll
    for (int mi = 0; mi < 4; ++mi) {
      const long rM = row0 + wr * 64 + mi * 16 + fg * 4;
#pragma unroll
      for (int reg = 0; reg < 4; ++reg) {
        const float v = acc[mi][n][reg] + bv;
        if (OUT_F32) Cf[(rM + reg) * 2048 + cN] = v;
        else         Cb[(rM + reg) * 2048 + cN] = f2bf(v);
      }
    }
  }
}

// ---------------- V transpose: V[b][s][h*128+d] -> Vt[(b*16+h)*128+d][s] ----------------
__global__ __launch_bounds__(256) void k_transpose_v(const u16* __restrict__ V,
                                                     u16* __restrict__ Vt) {
  __shared__ u16 t[64][68];
  const int bh = blockIdx.z;
  const long s0 = (long)blockIdx.x * 64;
  const long d0 = (long)blockIdx.y * 64;
  const int tid = threadIdx.x;
  const long rowbase = (long)(bh >> 4) * 2048;
  const int hcol = (bh & 15) * 128;
#pragma unroll
  for (int i = 0; i < 4; ++i) {
    const int v = tid + i * 256;
    const int r = v >> 4, c4 = (v & 15) << 2;
    const u16x4 val = *(const u16x4*)&V[(rowbase + s0 + r) * 2048 + hcol + d0 + c4];
    *(u16x4*)&t[r][c4] = val;
  }
  __syncthreads();
#pragma unroll
  for (int i = 0; i < 4; ++i) {
    const int v = tid + i * 256;
    const int dr = v >> 4, s4 = (v & 15) << 2;
    u16x4 o;
    o.x = t[s4 + 0][dr]; o.y = t[s4 + 1][dr]; o.z = t[s4 + 2][dr]; o.w = t[s4 + 3][dr];
    *(u16x4*)&Vt[((long)bh * 128 + d0 + dr) * 2048 + s0 + s4] = o;
  }
}

// ---------------- causal flash attention (unchanged from round 3) ----------------
__global__ __launch_bounds__(512) void k_flash_attn(
    const u16* __restrict__ Q, const u16* __restrict__ K, const u16* __restrict__ Vt,
    u16* __restrict__ O)
{
  __shared__ alignas(16) u16 Kt[2][8192];    // [64 kv][128 d], swizzled
  __shared__ alignas(16) u16 Vtt[2][8192];   // [128 d][64 s], swizzled
  __shared__ alignas(16) u16 Plds[8][16][72];

  const int tid = threadIdx.x;
  const int lane = tid & 63, wid = tid >> 6;
  const int fr = lane & 15, fg = lane >> 4;

  const int L = blockIdx.x;
  const int bh = (L & 7) * 4 + ((L >> 3) & 3);
  const int bx = L >> 5;

  const long rowbase = (long)(bh >> 4) * 2048;
  const int hcol = (bh & 15) * 128;
  const u16* Kg = K + rowbase * 2048 + hcol;
  const u16* Vg = Vt + (long)bh * 128 * 2048;
  const float scale2 = 0.08838834764831845f * 1.44269504089f;  // 1/sqrt(128) * log2(e)

  int kR[2], kC[2], vR[2], vC[2];
#pragma unroll
  for (int i = 0; i < 2; ++i) {
    const int chunk = (wid * 2 + i) * 64 + lane;
    kR[i] = chunk >> 4;
    kC[i] = ((chunk & 15) ^ (kR[i] & 7)) << 3;
    vR[i] = chunk >> 3;
    vC[i] = ((chunk & 7) ^ (vR[i] & 7)) << 3;
  }

  const int sw = fr & 7;
  int kbase[4], vbase[2];
#pragma unroll
  for (int c = 0; c < 4; ++c) kbase[c] = fr * 128 + (((c * 4 + fg) ^ sw) << 3);
#pragma unroll
  for (int kc = 0; kc < 2; ++kc) vbase[kc] = fr * 64 + (((kc * 4 + fg) ^ sw) << 3);

  for (int pass = 0; pass < 2; ++pass) {
    const int qblk = pass ? (15 - bx) : bx;
    const int n = 2 * (qblk + 1);
    const int q_lo = qblk * 128 + wid * 16;

    bf16x8 qf[4];
#pragma unroll
    for (int c = 0; c < 4; ++c)
      qf[c] = *(const bf16x8*)&Q[(rowbase + q_lo + fr) * 2048 + hcol + c * 32 + fg * 8];

    f32x4 oacc[8] = {};
    float m_run[4], l_run[4];
#pragma unroll
    for (int r = 0; r < 4; ++r) { m_run[r] = -1e30f; l_run[r] = 0.0f; }

#pragma unroll
    for (int i = 0; i < 2; ++i) {
      gload16(Kg + (long)kR[i] * 2048 + kC[i], &Kt[0][(wid * 2 + i) * 512]);
      gload16(Vg + (long)vR[i] * 2048 + vC[i], &Vtt[0][(wid * 2 + i) * 512]);
    }

    int cur = 0;
    for (int j = 0; j < n; ++j) {
      if (j + 1 < n) {
        const long kv = (long)(j + 1) * 64;
#pragma unroll
        for (int i = 0; i < 2; ++i) {
          gload16(Kg + (kv + kR[i]) * 2048 + kC[i], &Kt[cur ^ 1][(wid * 2 + i) * 512]);
          gload16(Vg + (long)vR[i] * 2048 + kv + vC[i], &Vtt[cur ^ 1][(wid * 2 + i) * 512]);
        }
        asm volatile("s_waitcnt vmcnt(4)" ::: "memory");
      } else {
        asm volatile("s_waitcnt vmcnt(0)" ::: "memory");
      }
      __builtin_amdgcn_s_barrier();
      __builtin_amdgcn_sched_barrier(0);

      const int kvlo = j * 64;
      const bool skip = (kvlo >= q_lo + 16);
      if (!skip) {
        const bool needmask = (kvlo + 63 > q_lo);

        f32x4 st[4] = {};
        const u16* kt = Kt[cur];
#pragma unroll
        for (int t = 0; t < 4; ++t)
#pragma unroll
          for (int c = 0; c < 4; ++c) {
            const bf16x8 kf = *(const bf16x8*)&kt[kbase[c] + t * 2048];
            st[t] = __builtin_amdgcn_mfma_f32_16x16x32_bf16(qf[c], kf, st[t], 0, 0, 0);
          }

        float pmax[4] = {-1e30f, -1e30f, -1e30f, -1e30f};
        if (needmask) {
#pragma unroll
          for (int t = 0; t < 4; ++t) {
            const int kg = kvlo + t * 16 + fr;
#pragma unroll
            for (int r = 0; r < 4; ++r) {
              const int qg = q_lo + fg * 4 + r;
              const float v = (kg <= qg) ? st[t][r] * scale2 : -1e30f;
              st[t][r] = v;
              pmax[r] = fmaxf(pmax[r], v);
            }
          }
        } else {
#pragma unroll
          for (int t = 0; t < 4; ++t)
#pragma unroll
            for (int r = 0; r < 4; ++r) {
              const float v = st[t][r] * scale2;
              st[t][r] = v;
              pmax[r] = fmaxf(pmax[r], v);
            }
        }
#pragma unroll
        for (int d = 1; d < 16; d <<= 1)
#pragma unroll
          for (int r = 0; r < 4; ++r) pmax[r] = fmaxf(pmax[r], __shfl_xor(pmax[r], d));

        const int ok = (pmax[0] <= m_run[0] + 8.f) & (pmax[1] <= m_run[1] + 8.f) &
                       (pmax[2] <= m_run[2] + 8.f) & (pmax[3] <= m_run[3] + 8.f);
        if (!__all(ok)) {
#pragma unroll
          for (int r = 0; r < 4; ++r) {
            const float nm = fmaxf(m_run[r], pmax[r]);
            const float al = exp2f(m_run[r] - nm);
            l_run[r] *= al;
            m_run[r] = nm;
#pragma unroll
            for (int dt = 0; dt < 8; ++dt) oacc[dt][r] *= al;
          }
        }

        float lsum[4] = {0.f, 0.f, 0.f, 0.f};
#pragma unroll
        for (int t = 0; t < 4; ++t)
#pragma unroll
          for (int r = 0; r < 4; ++r) {
            const float p = exp2f(st[t][r] - m_run[r]);
            st[t][r] = p;
            lsum[r] += p;
          }
#pragma unroll
        for (int d = 1; d < 16; d <<= 1)
#pragma unroll
          for (int r = 0; r < 4; ++r) lsum[r] += __shfl_xor(lsum[r], d);
#pragma unroll
        for (int r = 0; r < 4; ++r) l_run[r] += lsum[r];

#pragma unroll
        for (int t = 0; t < 4; ++t)
#pragma unroll
          for (int r = 0; r < 4; ++r)
            Plds[wid][fg * 4 + r][t * 16 + fr] = f2bf(st[t][r]);
        asm volatile("s_waitcnt lgkmcnt(0)" ::: "memory");
        __builtin_amdgcn_sched_barrier(0);

        const u16* vt = Vtt[cur];
#pragma unroll
        for (int kc = 0; kc < 2; ++kc) {
          const bf16x8 pf = *(const bf16x8*)&Plds[wid][fr][kc * 32 + fg * 8];
#pragma unroll
          for (int dt = 0; dt < 8; ++dt) {
            const bf16x8 vf = *(const bf16x8*)&vt[vbase[kc] + dt * 1024];
            oacc[dt] = __builtin_amdgcn_mfma_f32_16x16x32_bf16(pf, vf, oacc[dt], 0, 0, 0);
          }
        }
      }

      asm volatile("" ::: "memory");
      __builtin_amdgcn_s_barrier();
      cur ^= 1;
    }

    float inv[4];
#pragma unroll
    for (int r = 0; r < 4; ++r) inv[r] = 1.0f / l_run[r];
#pragma unroll
    for (int dt = 0; dt < 8; ++dt)
#pragma unroll
      for (int r = 0; r < 4; ++r)
        O[(rowbase + q_lo + fg * 4 + r) * 2048 + hcol + dt * 16 + fr] = f2bf(oacc[dt][r] * inv[r]);
  }
}

extern "C" void kernel_launch(void* const* d_in, const int* in_sizes, int n_in,
                              void* d_out, int out_size, void* d_ws, size_t ws_size,
                              hipStream_t stream) {
  const float* x  = (const float*)d_in[0];
  const float* Wq = (const float*)d_in[1];
  const float* bq = (const float*)d_in[2];
  const float* Wk = (const float*)d_in[3];
  const float* bk = (const float*)d_in[4];
  const float* Wv = (const float*)d_in[5];
  const float* bv = (const float*)d_in[6];
  const float* Wo = (const float*)d_in[7];
  const float* bo = (const float*)d_in[8];
  float* out = (float*)d_out;

  char* ws = (char*)d_ws;
  const size_t SZ_X = 16777216;   // 8M bf16
  const size_t SZ_W = 8388608;    // 4M bf16
  u16* xb  = (u16*)(ws);
  u16* wqb = (u16*)(ws + SZ_X);                 // wq/wk/wv contiguous = [6144][2048]
  u16* wkb = (u16*)(ws + SZ_X + 1 * SZ_W);
  u16* wvb = (u16*)(ws + SZ_X + 2 * SZ_W);
  u16* wob = (u16*)(ws + SZ_X + 3 * SZ_W);
  u16* Qb  = (u16*)(ws + 1 * SZ_X + 4 * SZ_W);
  u16* Kb  = (u16*)(ws + 2 * SZ_X + 4 * SZ_W);
  u16* Vb  = (u16*)(ws + 3 * SZ_X + 4 * SZ_W);
  u16* Vtb = (u16*)(ws + 4 * SZ_X + 4 * SZ_W);
  u16* Ob  = Vb;   // V dead after transpose; reuse for attention output

  k_f2bf5<<<dim3(1024, 5), 256, 0, stream>>>(x, Wq, Wk, Wv, Wo,
                                             xb, wqb, wkb, wvb, wob,
                                             8388608 / 4, 4194304 / 4);

  // fused QKV: M=4096 x N=6144 x K=2048; 32x24 = 768 blocks (3 full rounds)
  k_gemm256<0><<<768, 512, 0, stream>>>(xb, wqb, bq, bk, bv, Qb, Kb, Vb, nullptr, 32);

  k_transpose_v<<<dim3(32, 2, 32), 256, 0, stream>>>(Vb, Vtb);

  k_flash_attn<<<256, 512, 0, stream>>>(Qb, Kb, Vtb, Ob);

  // output projection (fp32 out): 32x8 = 256 blocks (1 full round)
  k_gemm256<1><<<256, 512, 0, stream>>>(Ob, wob, bo, bo, bo, nullptr, nullptr, nullptr, out, 32);
}

// Round 6
// 274.612 us; speedup vs baseline: 1.1757x; 1.0798x over previous
//
#include <hip/hip_runtime.h>

typedef unsigned short u16;
typedef __attribute__((ext_vector_type(8))) short bf16x8;
typedef __attribute__((ext_vector_type(4))) float f32x4;
typedef __attribute__((ext_vector_type(4))) unsigned short u16x4;

__device__ __forceinline__ u16 f2bf(float f) {
  union { float f; unsigned u; } v; v.f = f;
  return (u16)((v.u + 0x7FFFu + ((v.u >> 16) & 1u)) >> 16);
}

__device__ __forceinline__ void gload16(const u16* g, u16* l) {
  __builtin_amdgcn_global_load_lds((const __attribute__((address_space(1))) void*)g,
                                   (__attribute__((address_space(3))) void*)l, 16, 0, 0);
}

// ---------------- fp32 -> bf16 convert (5 tensors fused) ----------------
__global__ __launch_bounds__(256) void k_f2bf5(
    const float* __restrict__ i0, const float* __restrict__ i1, const float* __restrict__ i2,
    const float* __restrict__ i3, const float* __restrict__ i4,
    u16* o0, u16* o1, u16* o2, u16* o3, u16* o4, int n4x, int n4w) {
  const int seg = blockIdx.y;
  const float* in = (seg == 0) ? i0 : (seg == 1) ? i1 : (seg == 2) ? i2 : (seg == 3) ? i3 : i4;
  u16* out = (seg == 0) ? o0 : (seg == 1) ? o1 : (seg == 2) ? o2 : (seg == 3) ? o3 : o4;
  const int n4 = (seg == 0) ? n4x : n4w;
  int i = blockIdx.x * 256 + threadIdx.x;
  const int stride = gridDim.x * 256;
  for (; i < n4; i += stride) {
    const float4 v = ((const float4*)in)[i];
    u16x4 o;
    o.x = f2bf(v.x); o.y = f2bf(v.y); o.z = f2bf(v.z); o.w = f2bf(v.w);
    ((u16x4*)out)[i] = o;
  }
}

// ---------------- 128x256 GEMM, reads-after-barrier counted-vmcnt pipeline ----------------
// C[M,2048-seg] = A[M,2048] * Bt[N,2048]^T + bias. 512 thr = 8 waves (2M x 4N),
// per-wave 64x64 out (4x4 16x16 frags). BK=64, LDS 96 KiB dbuf, T2 XOR swizzle.
// Staging units (2 loads/thr each): U_A = A-tile, U_Blo = B rows (r&63)<32,
// U_Bhi = B rows (r&63)>=32.  Issue: P0 -> {A,Blo}(t+1), P1 -> {Bhi}(t+1).
// Waits (oldest-first accounting): P0 after issue: 10 in flight, need 4 oldest
// done -> vmcnt(6). P1 after issue: 8 in flight, need 2 oldest -> vmcnt(6).
// Phase: stage -> vmcnt(6) -> s_barrier -> ds_read -> lgkm0 -> 16 MFMA.
// Barrier VALIDATES the data the following reads consume; one barrier/phase.
// WAR safe: {A,Blo} vs {Bhi} regions disjoint; max skew = 1 barrier interval.
#define STAGE_P0(AN, BN_, kofs) do { _Pragma("unroll") \
  for (int i = 0; i < 2; ++i) { \
    gload16(A  + (row0 + aRow[i]) * 2048L + (kofs) + aCol[i], &(AN)[aDst[i]]); \
    gload16(Bt + (col0 + brLo[i]) * 2048L + (kofs) + bcB[i], &(BN_)[bDstLo[i]]); } } while (0)

#define STAGE_P1(BN_, kofs) do { _Pragma("unroll") \
  for (int i = 0; i < 2; ++i) \
    gload16(Bt + (col0 + brLo[i] + 32) * 2048L + (kofs) + bcB[i], &(BN_)[bDstLo[i] + 2048]); } while (0)

#define MMpair(nbase) do { _Pragma("unroll") \
  for (int mi = 0; mi < 4; ++mi) { _Pragma("unroll") \
    for (int nn = 0; nn < 2; ++nn) { \
      acc[mi][(nbase) + nn] = __builtin_amdgcn_mfma_f32_16x16x32_bf16( \
          a[mi][0], b[nn][0], acc[mi][(nbase) + nn], 0, 0, 0); \
      acc[mi][(nbase) + nn] = __builtin_amdgcn_mfma_f32_16x16x32_bf16( \
          a[mi][1], b[nn][1], acc[mi][(nbase) + nn], 0, 0, 0); } } } while (0)

#define TILE(AS, BS, AN, BN_, tn) do { \
  /* ---- phase 0: validate {A,Blo}(cur); compute n-lo half ---- */ \
  if ((tn) < 32) { STAGE_P0(AN, BN_, (long)(tn) << 6); \
    asm volatile("s_waitcnt vmcnt(6)" ::: "memory"); \
  } else { asm volatile("s_waitcnt vmcnt(2)" ::: "memory"); } \
  __builtin_amdgcn_s_barrier(); \
  asm volatile("" ::: "memory"); \
  _Pragma("unroll") for (int mi = 0; mi < 4; ++mi) { \
    a[mi][0] = *(const bf16x8*)&(AS)[aBase + mi * 1024 + pc0]; \
    a[mi][1] = *(const bf16x8*)&(AS)[aBase + mi * 1024 + pc1]; } \
  _Pragma("unroll") for (int nn = 0; nn < 2; ++nn) { \
    b[nn][0] = *(const bf16x8*)&(BS)[bBase + nn * 1024 + pc0]; \
    b[nn][1] = *(const bf16x8*)&(BS)[bBase + nn * 1024 + pc1]; } \
  asm volatile("s_waitcnt lgkmcnt(0)" ::: "memory"); \
  __builtin_amdgcn_sched_barrier(0); \
  __builtin_amdgcn_s_setprio(1); MMpair(0); __builtin_amdgcn_s_setprio(0); \
  /* ---- phase 1: validate {Bhi}(cur); compute n-hi half ---- */ \
  if ((tn) < 32) { STAGE_P1(BN_, (long)(tn) << 6); \
    asm volatile("s_waitcnt vmcnt(6)" ::: "memory"); \
  } else { asm volatile("s_waitcnt vmcnt(0)" ::: "memory"); } \
  __builtin_amdgcn_s_barrier(); \
  asm volatile("" ::: "memory"); \
  _Pragma("unroll") for (int nn = 0; nn < 2; ++nn) { \
    b[nn][0] = *(const bf16x8*)&(BS)[bBase + (2 + nn) * 1024 + pc0]; \
    b[nn][1] = *(const bf16x8*)&(BS)[bBase + (2 + nn) * 1024 + pc1]; } \
  asm volatile("s_waitcnt lgkmcnt(0)" ::: "memory"); \
  __builtin_amdgcn_sched_barrier(0); \
  __builtin_amdgcn_s_setprio(1); MMpair(2); __builtin_amdgcn_s_setprio(0); \
} while (0)

template <int OUT_F32>
__global__ __launch_bounds__(512, 2) void k_gemm128(
    const u16* __restrict__ A, const u16* __restrict__ Bt,
    const float* __restrict__ b0, const float* __restrict__ b1, const float* __restrict__ b2,
    u16* __restrict__ C0, u16* __restrict__ C1, u16* __restrict__ C2,
    float* __restrict__ Cf, int NBM)
{
  __shared__ alignas(16) u16 A0s[8192], B0s[16384], A1s[8192], B1s[16384];

  const int tid = threadIdx.x;
  const int lane = tid & 63, wid = tid >> 6;
  const int fr = lane & 15, fg = lane >> 4;
  const int wr = wid >> 2, wc = wid & 3;

  // bijective XCD-chunked block mapping: consecutive wgid share an XCD
  const int nblk = gridDim.x;
  const int q = nblk >> 3, r = nblk & 7;
  const int xcd = blockIdx.x & 7, lid = blockIdx.x >> 3;
  const int wgid = (xcd < r ? xcd * (q + 1) : r * (q + 1) + (xcd - r) * q) + lid;
  const int mb = wgid % NBM, nb = wgid / NBM;
  const long row0 = (long)mb * 128;
  const long col0 = (long)nb * 256;

  // staging assignment (2 chunk-ids per thread)
  int aRow[2], aCol[2], brLo[2], bcB[2], aDst[2], bDstLo[2];
#pragma unroll
  for (int i = 0; i < 2; ++i) {
    const int g = (wid * 2 + i) * 64 + lane;          // 0..1023
    aRow[i] = g >> 3;                                  // A: 128 rows x 8 chunks
    aCol[i] = ((g & 7) ^ (aRow[i] & 7)) << 3;
    aDst[i] = g * 8;                                   // u16 units
    const int stripe = g >> 8, rowin = (g >> 3) & 31;  // B-low: 4 stripes of 32 rows
    brLo[i] = stripe * 64 + rowin;
    bcB[i] = ((g & 7) ^ (brLo[i] & 7)) << 3;           // (row+32)&7 == row&7
    bDstLo[i] = stripe * 4096 + (g & 255) * 8;         // u16 units
  }

  // ds_read bases (u16 units), T2-swizzled chunk offsets
  const int sw = fr & 7;
  const int aBase = (wr * 64 + fr) * 64;
  const int bBase = (wc * 64 + fr) * 64;
  const int pc0 = (fg ^ sw) << 3;
  const int pc1 = ((4 + fg) ^ sw) << 3;

  f32x4 acc[4][4] = {};
  bf16x8 a[4][2], b[2][2];

  // prologue: stage tile 0 (all three units); first TILE's wait+barrier validates
  STAGE_P0(A0s, B0s, 0);
  STAGE_P1(B0s, 0);

#pragma unroll 1
  for (int t = 0; t < 32; t += 2) {
    TILE(A0s, B0s, A1s, B1s, t + 1);
    TILE(A1s, B1s, A0s, B0s, t + 2);
  }

  // epilogue: C/D col = lane&15, row = (lane>>4)*4+reg; bias + segment select
  const int seg = (int)(col0 >> 11);
  const long colL = col0 & 2047;
  const float* bp = (seg == 0) ? b0 : (seg == 1) ? b1 : b2;
  u16* Cb = (seg == 0) ? C0 : (seg == 1) ? C1 : C2;
#pragma unroll
  for (int n = 0; n < 4; ++n) {
    const long cN = colL + wc * 64 + n * 16 + fr;
    const float bv = bp[cN];
#pragma unroll
    for (int mi = 0; mi < 4; ++mi) {
      const long rM = row0 + wr * 64 + mi * 16 + fg * 4;
#pragma unroll
      for (int reg = 0; reg < 4; ++reg) {
        const float v = acc[mi][n][reg] + bv;
        if (OUT_F32) Cf[(rM + reg) * 2048 + cN] = v;
        else         Cb[(rM + reg) * 2048 + cN] = f2bf(v);
      }
    }
  }
}

// ---------------- V transpose: V[b][s][h*128+d] -> Vt[(b*16+h)*128+d][s] ----------------
__global__ __launch_bounds__(256) void k_transpose_v(const u16* __restrict__ V,
                                                     u16* __restrict__ Vt) {
  __shared__ u16 t[64][68];
  const int bh = blockIdx.z;
  const long s0 = (long)blockIdx.x * 64;
  const long d0 = (long)blockIdx.y * 64;
  const int tid = threadIdx.x;
  const long rowbase = (long)(bh >> 4) * 2048;
  const int hcol = (bh & 15) * 128;
#pragma unroll
  for (int i = 0; i < 4; ++i) {
    const int v = tid + i * 256;
    const int r = v >> 4, c4 = (v & 15) << 2;
    const u16x4 val = *(const u16x4*)&V[(rowbase + s0 + r) * 2048 + hcol + d0 + c4];
    *(u16x4*)&t[r][c4] = val;
  }
  __syncthreads();
#pragma unroll
  for (int i = 0; i < 4; ++i) {
    const int v = tid + i * 256;
    const int dr = v >> 4, s4 = (v & 15) << 2;
    u16x4 o;
    o.x = t[s4 + 0][dr]; o.y = t[s4 + 1][dr]; o.z = t[s4 + 2][dr]; o.w = t[s4 + 3][dr];
    *(u16x4*)&Vt[((long)bh * 128 + d0 + dr) * 2048 + s0 + s4] = o;
  }
}

// ---------------- causal flash attention (unchanged) ----------------
__global__ __launch_bounds__(512) void k_flash_attn(
    const u16* __restrict__ Q, const u16* __restrict__ K, const u16* __restrict__ Vt,
    u16* __restrict__ O)
{
  __shared__ alignas(16) u16 Kt[2][8192];    // [64 kv][128 d], swizzled
  __shared__ alignas(16) u16 Vtt[2][8192];   // [128 d][64 s], swizzled
  __shared__ alignas(16) u16 Plds[8][16][72];

  const int tid = threadIdx.x;
  const int lane = tid & 63, wid = tid >> 6;
  const int fr = lane & 15, fg = lane >> 4;

  const int L = blockIdx.x;
  const int bh = (L & 7) * 4 + ((L >> 3) & 3);
  const int bx = L >> 5;

  const long rowbase = (long)(bh >> 4) * 2048;
  const int hcol = (bh & 15) * 128;
  const u16* Kg = K + rowbase * 2048 + hcol;
  const u16* Vg = Vt + (long)bh * 128 * 2048;
  const float scale2 = 0.08838834764831845f * 1.44269504089f;  // 1/sqrt(128) * log2(e)

  int kR[2], kC[2], vR[2], vC[2];
#pragma unroll
  for (int i = 0; i < 2; ++i) {
    const int chunk = (wid * 2 + i) * 64 + lane;
    kR[i] = chunk >> 4;
    kC[i] = ((chunk & 15) ^ (kR[i] & 7)) << 3;
    vR[i] = chunk >> 3;
    vC[i] = ((chunk & 7) ^ (vR[i] & 7)) << 3;
  }

  const int sw = fr & 7;
  int kbase[4], vbase[2];
#pragma unroll
  for (int c = 0; c < 4; ++c) kbase[c] = fr * 128 + (((c * 4 + fg) ^ sw) << 3);
#pragma unroll
  for (int kc = 0; kc < 2; ++kc) vbase[kc] = fr * 64 + (((kc * 4 + fg) ^ sw) << 3);

  for (int pass = 0; pass < 2; ++pass) {
    const int qblk = pass ? (15 - bx) : bx;
    const int n = 2 * (qblk + 1);
    const int q_lo = qblk * 128 + wid * 16;

    bf16x8 qf[4];
#pragma unroll
    for (int c = 0; c < 4; ++c)
      qf[c] = *(const bf16x8*)&Q[(rowbase + q_lo + fr) * 2048 + hcol + c * 32 + fg * 8];

    f32x4 oacc[8] = {};
    float m_run[4], l_run[4];
#pragma unroll
    for (int r = 0; r < 4; ++r) { m_run[r] = -1e30f; l_run[r] = 0.0f; }

#pragma unroll
    for (int i = 0; i < 2; ++i) {
      gload16(Kg + (long)kR[i] * 2048 + kC[i], &Kt[0][(wid * 2 + i) * 512]);
      gload16(Vg + (long)vR[i] * 2048 + vC[i], &Vtt[0][(wid * 2 + i) * 512]);
    }

    int cur = 0;
    for (int j = 0; j < n; ++j) {
      if (j + 1 < n) {
        const long kv = (long)(j + 1) * 64;
#pragma unroll
        for (int i = 0; i < 2; ++i) {
          gload16(Kg + (kv + kR[i]) * 2048 + kC[i], &Kt[cur ^ 1][(wid * 2 + i) * 512]);
          gload16(Vg + (long)vR[i] * 2048 + kv + vC[i], &Vtt[cur ^ 1][(wid * 2 + i) * 512]);
        }
        asm volatile("s_waitcnt vmcnt(4)" ::: "memory");
      } else {
        asm volatile("s_waitcnt vmcnt(0)" ::: "memory");
      }
      __builtin_amdgcn_s_barrier();
      __builtin_amdgcn_sched_barrier(0);

      const int kvlo = j * 64;
      const bool skip = (kvlo >= q_lo + 16);
      if (!skip) {
        const bool needmask = (kvlo + 63 > q_lo);

        f32x4 st[4] = {};
        const u16* kt = Kt[cur];
#pragma unroll
        for (int t = 0; t < 4; ++t)
#pragma unroll
          for (int c = 0; c < 4; ++c) {
            const bf16x8 kf = *(const bf16x8*)&kt[kbase[c] + t * 2048];
            st[t] = __builtin_amdgcn_mfma_f32_16x16x32_bf16(qf[c], kf, st[t], 0, 0, 0);
          }

        float pmax[4] = {-1e30f, -1e30f, -1e30f, -1e30f};
        if (needmask) {
#pragma unroll
          for (int t = 0; t < 4; ++t) {
            const int kg = kvlo + t * 16 + fr;
#pragma unroll
            for (int r = 0; r < 4; ++r) {
              const int qg = q_lo + fg * 4 + r;
              const float v = (kg <= qg) ? st[t][r] * scale2 : -1e30f;
              st[t][r] = v;
              pmax[r] = fmaxf(pmax[r], v);
            }
          }
        } else {
#pragma unroll
          for (int t = 0; t < 4; ++t)
#pragma unroll
            for (int r = 0; r < 4; ++r) {
              const float v = st[t][r] * scale2;
              st[t][r] = v;
              pmax[r] = fmaxf(pmax[r], v);
            }
        }
#pragma unroll
        for (int d = 1; d < 16; d <<= 1)
#pragma unroll
          for (int r = 0; r < 4; ++r) pmax[r] = fmaxf(pmax[r], __shfl_xor(pmax[r], d));

        const int ok = (pmax[0] <= m_run[0] + 8.f) & (pmax[1] <= m_run[1] + 8.f) &
                       (pmax[2] <= m_run[2] + 8.f) & (pmax[3] <= m_run[3] + 8.f);
        if (!__all(ok)) {
#pragma unroll
          for (int r = 0; r < 4; ++r) {
            const float nm = fmaxf(m_run[r], pmax[r]);
            const float al = exp2f(m_run[r] - nm);
            l_run[r] *= al;
            m_run[r] = nm;
#pragma unroll
            for (int dt = 0; dt < 8; ++dt) oacc[dt][r] *= al;
          }
        }

        float lsum[4] = {0.f, 0.f, 0.f, 0.f};
#pragma unroll
        for (int t = 0; t < 4; ++t)
#pragma unroll
          for (int r = 0; r < 4; ++r) {
            const float p = exp2f(st[t][r] - m_run[r]);
            st[t][r] = p;
            lsum[r] += p;
          }
#pragma unroll
        for (int d = 1; d < 16; d <<= 1)
#pragma unroll
          for (int r = 0; r < 4; ++r) lsum[r] += __shfl_xor(lsum[r], d);
#pragma unroll
        for (int r = 0; r < 4; ++r) l_run[r] += lsum[r];

#pragma unroll
        for (int t = 0; t < 4; ++t)
#pragma unroll
          for (int r = 0; r < 4; ++r)
            Plds[wid][fg * 4 + r][t * 16 + fr] = f2bf(st[t][r]);
        asm volatile("s_waitcnt lgkmcnt(0)" ::: "memory");
        __builtin_amdgcn_sched_barrier(0);

        const u16* vt = Vtt[cur];
#pragma unroll
        for (int kc = 0; kc < 2; ++kc) {
          const bf16x8 pf = *(const bf16x8*)&Plds[wid][fr][kc * 32 + fg * 8];
#pragma unroll
          for (int dt = 0; dt < 8; ++dt) {
            const bf16x8 vf = *(const bf16x8*)&vt[vbase[kc] + dt * 1024];
            oacc[dt] = __builtin_amdgcn_mfma_f32_16x16x32_bf16(pf, vf, oacc[dt], 0, 0, 0);
          }
        }
      }

      asm volatile("" ::: "memory");
      __builtin_amdgcn_s_barrier();
      cur ^= 1;
    }

    float inv[4];
#pragma unroll
    for (int r = 0; r < 4; ++r) inv[r] = 1.0f / l_run[r];
#pragma unroll
    for (int dt = 0; dt < 8; ++dt)
#pragma unroll
      for (int r = 0; r < 4; ++r)
        O[(rowbase + q_lo + fg * 4 + r) * 2048 + hcol + dt * 16 + fr] = f2bf(oacc[dt][r] * inv[r]);
  }
}

extern "C" void kernel_launch(void* const* d_in, const int* in_sizes, int n_in,
                              void* d_out, int out_size, void* d_ws, size_t ws_size,
                              hipStream_t stream) {
  const float* x  = (const float*)d_in[0];
  const float* Wq = (const float*)d_in[1];
  const float* bq = (const float*)d_in[2];
  const float* Wk = (const float*)d_in[3];
  const float* bk = (const float*)d_in[4];
  const float* Wv = (const float*)d_in[5];
  const float* bv = (const float*)d_in[6];
  const float* Wo = (const float*)d_in[7];
  const float* bo = (const float*)d_in[8];
  float* out = (float*)d_out;

  char* ws = (char*)d_ws;
  const size_t SZ_X = 16777216;   // 8M bf16
  const size_t SZ_W = 8388608;    // 4M bf16
  u16* xb  = (u16*)(ws);
  u16* wqb = (u16*)(ws + SZ_X);                 // wq/wk/wv contiguous = [6144][2048]
  u16* wkb = (u16*)(ws + SZ_X + 1 * SZ_W);
  u16* wvb = (u16*)(ws + SZ_X + 2 * SZ_W);
  u16* wob = (u16*)(ws + SZ_X + 3 * SZ_W);
  u16* Qb  = (u16*)(ws + 1 * SZ_X + 4 * SZ_W);
  u16* Kb  = (u16*)(ws + 2 * SZ_X + 4 * SZ_W);
  u16* Vb  = (u16*)(ws + 3 * SZ_X + 4 * SZ_W);
  u16* Vtb = (u16*)(ws + 4 * SZ_X + 4 * SZ_W);
  u16* Ob  = Vb;   // V dead after transpose; reuse for attention output

  k_f2bf5<<<dim3(1024, 5), 256, 0, stream>>>(x, Wq, Wk, Wv, Wo,
                                             xb, wqb, wkb, wvb, wob,
                                             8388608 / 4, 4194304 / 4);

  // fused QKV: M=4096 x N=6144 x K=2048; 32x24 = 768 blocks (3 full rounds)
  k_gemm128<0><<<768, 512, 0, stream>>>(xb, wqb, bq, bk, bv, Qb, Kb, Vb, nullptr, 32);

  k_transpose_v<<<dim3(32, 2, 32), 256, 0, stream>>>(Vb, Vtb);

  k_flash_attn<<<256, 512, 0, stream>>>(Qb, Kb, Vtb, Ob);

  // output projection (fp32 out): 32x8 = 256 blocks (1 full round)
  k_gemm128<1><<<256, 512, 0, stream>>>(Ob, wob, bo, bo, bo, nullptr, nullptr, nullptr, out, 32);
}